// Round 1
// baseline (553.226 us; speedup 1.0000x reference)
//
#include <hip/hip_runtime.h>
#include <math.h>

// Problem constants (fixed by setup_inputs): N=16384, D=4096, E=64, top_k=2.
constexpr int D_DIM = 4096;
constexpr int E_DIM = 64;     // = BN, = wavefront size
constexpr int BM    = 64;     // rows per block -> 16384/64 = 256 blocks (1 per CU)
constexpr int BK    = 64;     // k-chunk
constexpr int TM    = 4;      // rows per thread
constexpr int TN    = 4;      // cols per thread
constexpr int NTHREADS = 256; // (BM/TM)*(E/TN) = 16*16
constexpr int KTILES = D_DIM / BK;  // 64
constexpr int LDX = BM + 4;   // 68: pad keeps b128 16B-alignment (k*68+4*tm)
constexpr int LDW = E_DIM + 4;
constexpr int LDL = E_DIM + 1; // 65: epilogue logits, (row+e)%32 -> conflict-free scan

__global__ __launch_bounds__(NTHREADS) void topk_gate_kernel(
    const float* __restrict__ x, const float* __restrict__ W,
    const float* __restrict__ b, float* __restrict__ out, int N)
{
    // 2 k-major tiles: 2*64*68 floats = 34.8 KB; epilogue reuses the same space.
    __shared__ float smem[BK * LDX + BK * LDW];
    float* Xs = smem;             // [BK][LDX]  Xs[k][m]
    float* Ws = smem + BK * LDX;  // [BK][LDW]  Ws[k][e]

    const int tid  = threadIdx.x;
    const int tn   = tid & 15;          // col group: cols tn*4..+3
    const int tm   = tid >> 4;          // row group: rows tm*4..+3
    const int row0 = blockIdx.x * BM;

    // staging coords: thread covers 4 (row, float4-col) pairs per tile
    const int sr  = tid >> 4;           // 0..15
    const int sc4 = tid & 15;           // float4 column 0..15 (k-offset sc4*4)

    float acc[TM][TN];
#pragma unroll
    for (int i = 0; i < TM; ++i)
#pragma unroll
        for (int j = 0; j < TN; ++j) acc[i][j] = 0.0f;

    const float4 bias = *(reinterpret_cast<const float4*>(b) + tn);

    float4 xr[4], wr[4];

    const float* xblk = x + (size_t)row0 * D_DIM;

    // ---- prologue: load + store tile 0 ----
    {
        const float* xg = xblk;             // k0 = 0
        const float* wg = W;
#pragma unroll
        for (int p = 0; p < 4; ++p) {
            const int r = p * 16 + sr;
            xr[p] = *reinterpret_cast<const float4*>(xg + (size_t)r * D_DIM + sc4 * 4);
            wr[p] = *reinterpret_cast<const float4*>(wg + (size_t)r * D_DIM + sc4 * 4);
        }
#pragma unroll
        for (int p = 0; p < 4; ++p) {
            const int r = p * 16 + sr;
            const int k = sc4 * 4;
            Xs[(k + 0) * LDX + r] = xr[p].x;
            Xs[(k + 1) * LDX + r] = xr[p].y;
            Xs[(k + 2) * LDX + r] = xr[p].z;
            Xs[(k + 3) * LDX + r] = xr[p].w;
            Ws[(k + 0) * LDW + r] = wr[p].x;
            Ws[(k + 1) * LDW + r] = wr[p].y;
            Ws[(k + 2) * LDW + r] = wr[p].z;
            Ws[(k + 3) * LDW + r] = wr[p].w;
        }
    }
    __syncthreads();

    // ---- main loop: register-prefetch tile t+1 while computing tile t ----
    for (int t = 0; t < KTILES; ++t) {
        if (t + 1 < KTILES) {
            const int k0 = (t + 1) * BK;
            const float* xg = xblk + k0;
            const float* wg = W + k0;
#pragma unroll
            for (int p = 0; p < 4; ++p) {
                const int r = p * 16 + sr;
                xr[p] = *reinterpret_cast<const float4*>(xg + (size_t)r * D_DIM + sc4 * 4);
                wr[p] = *reinterpret_cast<const float4*>(wg + (size_t)r * D_DIM + sc4 * 4);
            }
        }

#pragma unroll 8
        for (int k = 0; k < BK; ++k) {
            const float4 xa = *reinterpret_cast<const float4*>(&Xs[k * LDX + tm * 4]);
            const float4 wb = *reinterpret_cast<const float4*>(&Ws[k * LDW + tn * 4]);
            acc[0][0] += xa.x * wb.x; acc[0][1] += xa.x * wb.y;
            acc[0][2] += xa.x * wb.z; acc[0][3] += xa.x * wb.w;
            acc[1][0] += xa.y * wb.x; acc[1][1] += xa.y * wb.y;
            acc[1][2] += xa.y * wb.z; acc[1][3] += xa.y * wb.w;
            acc[2][0] += xa.z * wb.x; acc[2][1] += xa.z * wb.y;
            acc[2][2] += xa.z * wb.z; acc[2][3] += xa.z * wb.w;
            acc[3][0] += xa.w * wb.x; acc[3][1] += xa.w * wb.y;
            acc[3][2] += xa.w * wb.z; acc[3][3] += xa.w * wb.w;
        }
        __syncthreads();
        if (t + 1 < KTILES) {
#pragma unroll
            for (int p = 0; p < 4; ++p) {
                const int r = p * 16 + sr;
                const int k = sc4 * 4;
                Xs[(k + 0) * LDX + r] = xr[p].x;
                Xs[(k + 1) * LDX + r] = xr[p].y;
                Xs[(k + 2) * LDX + r] = xr[p].z;
                Xs[(k + 3) * LDX + r] = xr[p].w;
                Ws[(k + 0) * LDW + r] = wr[p].x;
                Ws[(k + 1) * LDW + r] = wr[p].y;
                Ws[(k + 2) * LDW + r] = wr[p].z;
                Ws[(k + 3) * LDW + r] = wr[p].w;
            }
        }
        __syncthreads();
    }

    // ---- epilogue: logits -> LDS, per-row top-2, softmax, scatter ----
    float* Ls   = smem;                 // [BM][LDL]
    float* aux  = smem + BM * LDL;      // i1[64], i2[64], p1[64], p2[64]

#pragma unroll
    for (int i = 0; i < TM; ++i) {
        const int m = tm * 4 + i;
        Ls[m * LDL + tn * 4 + 0] = acc[i][0] + bias.x;
        Ls[m * LDL + tn * 4 + 1] = acc[i][1] + bias.y;
        Ls[m * LDL + tn * 4 + 2] = acc[i][2] + bias.z;
        Ls[m * LDL + tn * 4 + 3] = acc[i][3] + bias.w;
    }
    __syncthreads();

    if (tid < BM) {
        const float* lr = &Ls[tid * LDL];
        float v1 = -INFINITY, v2 = -INFINITY;
        int i1 = 0, i2 = 0;
        // strict '>' reproduces lax.top_k tie-breaking (lowest index first)
        for (int e = 0; e < E_DIM; ++e) {
            const float v = lr[e];
            if (v > v1)      { v2 = v1; i2 = i1; v1 = v; i1 = e; }
            else if (v > v2) { v2 = v;  i2 = e; }
        }
        const float ex = expf(v2 - v1);       // <= 1, no overflow
        const float dn = 1.0f + ex;
        const float p1 = 1.0f / dn;
        const float p2 = ex / dn;
        aux[tid]       = (float)i1;
        aux[64 + tid]  = (float)i2;
        aux[128 + tid] = p1;
        aux[192 + tid] = p2;
        // top_idx output chunk (written as float values; buffer read as fp32)
        const size_t base = (size_t)N * E_DIM + (size_t)(row0 + tid) * 2;
        out[base]     = (float)i1;
        out[base + 1] = (float)i2;
    }
    __syncthreads();

    // gate matrix: 64 rows x 16 float4, fully written (zeros included)
#pragma unroll
    for (int p = 0; p < 4; ++p) {
        const int f4 = p * 256 + tid;
        const int r  = f4 >> 4;
        const int c4 = f4 & 15;
        const int i1 = (int)aux[r];
        const int i2 = (int)aux[64 + r];
        const float p1 = aux[128 + r];
        const float p2 = aux[192 + r];
        const int e = c4 * 4;
        float4 g;
        g.x = (e + 0 == i1) ? p1 : (e + 0 == i2) ? p2 : 0.0f;
        g.y = (e + 1 == i1) ? p1 : (e + 1 == i2) ? p2 : 0.0f;
        g.z = (e + 2 == i1) ? p1 : (e + 2 == i2) ? p2 : 0.0f;
        g.w = (e + 3 == i1) ? p1 : (e + 3 == i2) ? p2 : 0.0f;
        *reinterpret_cast<float4*>(out + (size_t)(row0 + r) * E_DIM + e) = g;
    }
}

extern "C" void kernel_launch(void* const* d_in, const int* in_sizes, int n_in,
                              void* d_out, int out_size, void* d_ws, size_t ws_size,
                              hipStream_t stream) {
    const float* x = (const float*)d_in[0];
    const float* W = (const float*)d_in[1];
    const float* b = (const float*)d_in[2];
    float* out = (float*)d_out;
    const int N = in_sizes[0] / D_DIM;       // 16384
    dim3 grid(N / BM), block(NTHREADS);
    hipLaunchKernelGGL(topk_gate_kernel, grid, block, 0, stream, x, W, b, out, N);
}